// Round 1
// baseline (116.934 us; speedup 1.0000x reference)
//
#include <hip/hip_runtime.h>

// ---- problem constants ----
#define NCAM      6
#define NB        4
#define NROWS     24          // NB*NCAM
#define NQ        65536       // 256*256
#define MAXLEN_   65536
#define CHUNK     1024
#define NCHUNK    64          // NQ / CHUNK
#define QPT       4           // q's per thread (256 threads * 4 = 1024 = CHUNK)

// flat f32 offsets into d_out (return order)
#define OFF_QGRID   0
#define OFF_RESTORE 3145728    // 24*65536*2
#define OFF_REFPTS  6291456    // + 4*6*256*256*2
#define OFF_COUNTS  18874368   // + 24*65536*4*2

// z values of the 4 pillar points, f32-linspace path:
// zs=linspace(0.5,7.5,4) in f32, z = zs/8*8 - 5
__device__ __forceinline__ float zval(int d) {
    const float z[4] = { -4.5f, -2.16666674613952637f,
                          0.166666507720947266f, 2.5f };
    return z[d];
}

__device__ __forceinline__ float clip21(float x) {
    return fminf(fmaxf(x, -2.1f), 2.1f);
}

// project one 3D point through rows 0..2 of the 4x4 matrix; returns vis
__device__ __forceinline__ bool proj_point(const float m[12], float x, float y, float z,
                                           float& u, float& v) {
    float c0 = ((m[0]*x + m[1]*y) + m[2]*z) + m[3];
    float c1 = ((m[4]*x + m[5]*y) + m[6]*z) + m[7];
    float c2 = ((m[8]*x + m[9]*y) + m[10]*z) + m[11];
    float zcl = fmaxf(c2, 1e-5f);
    u = (c0 / zcl) / 928.0f;   // IMW
    v = (c1 / zcl) / 512.0f;   // IMH
    return (c2 > 1e-5f) & (v > 0.0f) & (v < 1.0f) & (u < 1.0f) & (u > 0.0f);
}

__device__ __forceinline__ void load_mat(const float* __restrict__ ego2img, int row, float m[12]) {
    const float* M = ego2img + row * 16;
    #pragma unroll
    for (int i = 0; i < 12; ++i) m[i] = M[i];
}

__device__ __forceinline__ void bev_xy(int q, int& qx, int& qy, float& x, float& y) {
    qx = q & 255; qy = q >> 8;
    x = ((float)qx + 0.5f) * (1.0f/256.0f) * 102.4f - 51.2f;
    y = ((float)qy + 0.5f) * (1.0f/256.0f) * 102.4f - 51.2f;
}

// ---------- kernel 1: per-chunk visible-pillar counts ----------
__global__ void __launch_bounds__(256)
k_count(const float* __restrict__ ego2img, int* __restrict__ chunkCounts)
{
    int chunk = blockIdx.x, row = blockIdx.y;
    float m[12]; load_mat(ego2img, row, m);
    int t = threadIdx.x;
    int q0 = chunk * CHUNK + t * QPT;
    int cnt = 0;
    #pragma unroll
    for (int i = 0; i < QPT; ++i) {
        int q = q0 + i, qx, qy; float x, y;
        bev_xy(q, qx, qy, x, y);
        bool va = false;
        #pragma unroll
        for (int d = 0; d < 4; ++d) {
            float u, v;
            va |= proj_point(m, x, y, zval(d), u, v);
        }
        cnt += va ? 1 : 0;
    }
    #pragma unroll
    for (int off = 32; off > 0; off >>= 1) cnt += __shfl_down(cnt, off, 64);
    __shared__ int wsum[4];
    if ((t & 63) == 0) wsum[t >> 6] = cnt;
    __syncthreads();
    if (t == 0) chunkCounts[row * NCHUNK + chunk] = wsum[0] + wsum[1] + wsum[2] + wsum[3];
}

// ---------- kernel 2: scan + packed scatter of queries grid / ref points ----------
__global__ void __launch_bounds__(256)
k_pack(const float* __restrict__ ego2img, const int* __restrict__ chunkCounts,
       int* __restrict__ visrank, float* __restrict__ out)
{
    int chunk = blockIdx.x, row = blockIdx.y;
    int t = threadIdx.x;
    __shared__ int sBase, sTotal;
    __shared__ int waveIncl[4];

    // wave 0: exclusive prefix over the row's 64 chunk counts
    if (t < 64) {
        int c = chunkCounts[row * NCHUNK + t];
        int incl = c;
        #pragma unroll
        for (int off = 1; off < 64; off <<= 1) {
            int n = __shfl_up(incl, off, 64);
            if (t >= off) incl += n;
        }
        if (t == chunk) sBase = incl - c;
        if (t == 63)    sTotal = incl;
    }

    float m[12]; load_mat(ego2img, row, m);
    int q0 = chunk * CHUNK + t * QPT;
    float uv[QPT][8];
    int vism = 0, cnt = 0;
    #pragma unroll
    for (int i = 0; i < QPT; ++i) {
        int q = q0 + i, qx, qy; float x, y;
        bev_xy(q, qx, qy, x, y);
        bool va = false;
        #pragma unroll
        for (int d = 0; d < 4; ++d) {
            float u, v;
            bool vi = proj_point(m, x, y, zval(d), u, v);
            uv[i][2*d]   = clip21(u);
            uv[i][2*d+1] = clip21(v);
            va |= vi;
        }
        if (va) { vism |= (1 << i); ++cnt; }
    }

    // block scan of per-thread counts
    int incl = cnt;
    #pragma unroll
    for (int off = 1; off < 64; off <<= 1) {
        int n = __shfl_up(incl, off, 64);
        if ((t & 63) >= off) incl += n;
    }
    int wid = t >> 6;
    if ((t & 63) == 63) waveIncl[wid] = incl;
    __syncthreads();
    int base = sBase, total = sTotal;
    #pragma unroll
    for (int w = 0; w < 3; ++w) if (w < wid) base += waveIncl[w];
    int r = base + incl - cnt;  // rank of this thread's first visible q

    float2* qgrid = (float2*)(out + OFF_QGRID  + (size_t)row * MAXLEN_ * 2);
    float4* refp  = (float4*)(out + OFF_REFPTS + (size_t)row * MAXLEN_ * 8);
    int*    vr    = visrank + row * NQ;

    #pragma unroll
    for (int i = 0; i < QPT; ++i) {
        int q = q0 + i;
        if ((vism >> i) & 1) {
            int qx = q & 255, qy = q >> 8;
            float2 g;
            g.x = ((float)qx / 255.0f) * 2.0f - 1.0f;
            g.y = ((float)qy / 255.0f) * 2.0f - 1.0f;
            qgrid[r] = g;
            refp[2*r]   = make_float4(uv[i][0], uv[i][1], uv[i][2], uv[i][3]);
            refp[2*r+1] = make_float4(uv[i][4], uv[i][5], uv[i][6], uv[i][7]);
            vr[q] = r;
            ++r;
        } else {
            vr[q] = -1;
        }
    }
    // tail fill: slots >= row total get defaults (covers whole array exactly once)
    #pragma unroll
    for (int i = 0; i < QPT; ++i) {
        int s = q0 + i;
        if (s >= total) {
            qgrid[s] = make_float2(-1.5f, -1.5f);
            float4 z4 = make_float4(0.f, 0.f, 0.f, 0.f);
            refp[2*s]   = z4;
            refp[2*s+1] = z4;
        }
    }
}

// ---------- kernel 3: restore grid + pillar counts ----------
__global__ void __launch_bounds__(256)
k_restore(const int* __restrict__ visrank, float* __restrict__ out)
{
    int idx = blockIdx.x * 256 + threadIdx.x;   // b*NQ + q, total NB*NQ
    int b = idx >> 16, q = idx & 65535;
    int qx = q & 255, qy = q >> 8;
    float2* rest = (float2*)(out + OFF_RESTORE + (size_t)b * (6 * 256 * 256 * 2));
    int over = 0;
    #pragma unroll
    for (int c = 0; c < NCAM; ++c) {
        int r = visrank[((b * NCAM + c) << 16) | q];
        if (r >= 0) {
            float gx = ((float)(r & 255) / 255.0f) * 2.0f - 1.0f;
            float gy = ((float)(c * 256 + (r >> 8)) / 1535.0f) * 2.0f - 1.0f;
            rest[(over * 256 + qy) * 256 + qx] = make_float2(gx, gy);
            ++over;
        }
    }
    for (int o = over; o < 6; ++o)
        rest[(o * 256 + qy) * 256 + qx] = make_float2(-1.5f, -1.5f);
    out[OFF_COUNTS + idx] = 1.0f / fmaxf((float)over, 1.0f);
}

extern "C" void kernel_launch(void* const* d_in, const int* in_sizes, int n_in,
                              void* d_out, int out_size, void* d_ws, size_t ws_size,
                              hipStream_t stream)
{
    const float* ego2img = (const float*)d_in[0];
    float* out = (float*)d_out;
    int* chunkCounts = (int*)d_ws;                     // 24*64 ints
    int* visrank     = (int*)((char*)d_ws + 8192);     // 24*65536 ints (~6.3 MB)

    dim3 grid(NCHUNK, NROWS);
    k_count  <<<grid, 256, 0, stream>>>(ego2img, chunkCounts);
    k_pack   <<<grid, 256, 0, stream>>>(ego2img, chunkCounts, visrank, out);
    k_restore<<<(NB * NQ) / 256, 256, 0, stream>>>(visrank, out);
}

// Round 2
// 99.433 us; speedup vs baseline: 1.1760x; 1.1760x over previous
//
#include <hip/hip_runtime.h>

// ---- problem constants ----
#define NCAM      6
#define NB        4
#define NROWS     24          // NB*NCAM
#define NQ        65536       // 256*256
#define MAXLEN_   65536

// flat f32 offsets into d_out (return order)
#define OFF_QGRID   0
#define OFF_RESTORE 3145728    // 24*65536*2
#define OFF_REFPTS  6291456    // + 4*6*256*256*2
#define OFF_COUNTS  18874368   // + 24*65536*4*2

// z values of the 4 pillar points, f32-linspace path
__device__ __forceinline__ float zval(int d) {
    const float z[4] = { -4.5f, -2.16666674613952637f,
                          0.166666507720947266f, 2.5f };
    return z[d];
}

__device__ __forceinline__ float clip21(float x) {
    return fminf(fmaxf(x, -2.1f), 2.1f);
}

// project one 3D point through rows 0..2 of the 4x4 matrix; returns vis
// (kept bit-identical to the round-1 passing version)
__device__ __forceinline__ bool proj_point(const float m[12], float x, float y, float z,
                                           float& u, float& v) {
    float c0 = ((m[0]*x + m[1]*y) + m[2]*z) + m[3];
    float c1 = ((m[4]*x + m[5]*y) + m[6]*z) + m[7];
    float c2 = ((m[8]*x + m[9]*y) + m[10]*z) + m[11];
    float zcl = fmaxf(c2, 1e-5f);
    u = (c0 / zcl) / 928.0f;   // IMW
    v = (c1 / zcl) / 512.0f;   // IMH
    return (c2 > 1e-5f) & (v > 0.0f) & (v < 1.0f) & (u < 1.0f) & (u > 0.0f);
}

__device__ __forceinline__ void load_mat(const float* __restrict__ ego2img, int row, float m[12]) {
    const float* M = ego2img + row * 16;
    #pragma unroll
    for (int i = 0; i < 12; ++i) m[i] = M[i];
}

__device__ __forceinline__ void bev_xy(int qx, int qy, float& x, float& y) {
    x = ((float)qx + 0.5f) * (1.0f/256.0f) * 102.4f - 51.2f;
    y = ((float)qy + 0.5f) * (1.0f/256.0f) * 102.4f - 51.2f;
}

// ---------- kernel 1: per-256q-subchunk visible-pillar counts ----------
// grid (64, 24), 256 threads. Each wave owns 256 consecutive q -> one count.
__global__ void __launch_bounds__(256)
k_count(const float* __restrict__ ego2img, int* __restrict__ chunkCounts)
{
    int chunk = blockIdx.x, row = blockIdx.y;
    float m[12]; load_mat(ego2img, row, m);
    int t = threadIdx.x;
    int q0 = chunk * 1024 + t * 4;
    int cnt = 0;
    #pragma unroll
    for (int i = 0; i < 4; ++i) {
        int q = q0 + i;
        float x, y; bev_xy(q & 255, q >> 8, x, y);
        bool va = false;
        #pragma unroll
        for (int d = 0; d < 4; ++d) {
            float u, v;
            va |= proj_point(m, x, y, zval(d), u, v);
        }
        cnt += va ? 1 : 0;
    }
    #pragma unroll
    for (int off = 32; off > 0; off >>= 1) cnt += __shfl_down(cnt, off, 64);
    if ((t & 63) == 0)
        chunkCounts[row * 256 + chunk * 4 + (t >> 6)] = cnt;
}

// ---------- kernel 2: fused pack + restore + counts ----------
// grid (256, NB), 256 threads. Block = one BEV row (qy = blockIdx.x) of one
// batch, all 6 cameras. Per-camera ranks live in LDS; no global visrank.
__global__ void __launch_bounds__(256)
k_fused(const float* __restrict__ ego2img, const int* __restrict__ chunkCounts,
        float* __restrict__ out)
{
    int chunk = blockIdx.x, b = blockIdx.y;
    int t = threadIdx.x;
    int lane = t & 63, wid = t >> 6;

    __shared__ int sBase[NCAM], sTotal[NCAM];
    __shared__ int waveIncl[NCAM][4];
    __shared__ int ranks[NCAM][256];

    // phase 0: per-camera exclusive prefix over the row's 256 subchunk counts
    for (int c = wid; c < NCAM; c += 4) {
        const int* p = chunkCounts + (b * NCAM + c) * 256;
        int4 v4 = ((const int4*)p)[lane];            // 4 consecutive counts
        int s = v4.x + v4.y + v4.z + v4.w;
        int incl = s;
        #pragma unroll
        for (int off = 1; off < 64; off <<= 1) {
            int n = __shfl_up(incl, off, 64);
            if (lane >= off) incl += n;
        }
        if (lane == (chunk >> 2)) {
            int base = incl - s;
            int k = chunk & 3;
            if (k > 0) base += v4.x;
            if (k > 1) base += v4.y;
            if (k > 2) base += v4.z;
            sBase[c] = base;
        }
        if (lane == 63) sTotal[c] = incl;
    }

    int q  = chunk * 256 + t;       // this block: qy == chunk, qx == t
    int qx = t, qy = chunk;
    float x, y; bev_xy(qx, qy, x, y);

    // phase 1: per camera — project, scan, packed scatter, tail fill
    for (int c = 0; c < NCAM; ++c) {
        float m[12]; load_mat(ego2img, b * NCAM + c, m);
        float uv[8];
        bool vis = false;
        #pragma unroll
        for (int d = 0; d < 4; ++d) {
            float u, v;
            bool vi = proj_point(m, x, y, zval(d), u, v);
            uv[2*d]   = clip21(u);
            uv[2*d+1] = clip21(v);
            vis |= vi;
        }
        int cnt = vis ? 1 : 0;
        int incl = cnt;
        #pragma unroll
        for (int off = 1; off < 64; off <<= 1) {
            int n = __shfl_up(incl, off, 64);
            if (lane >= off) incl += n;
        }
        if (lane == 63) waveIncl[c][wid] = incl;
        __syncthreads();
        int base = sBase[c];
        #pragma unroll
        for (int w = 0; w < 3; ++w) if (w < wid) base += waveIncl[c][w];
        int r = base + incl - cnt;   // packed rank of this q if visible

        float2* qgrid = (float2*)(out + OFF_QGRID)  + (size_t)(b * NCAM + c) * MAXLEN_;
        float4* refp  = (float4*)(out + OFF_REFPTS) + (size_t)(b * NCAM + c) * MAXLEN_ * 2;

        if (vis) {
            float2 g;
            g.x = ((float)qx / 255.0f) * 2.0f - 1.0f;
            g.y = ((float)qy / 255.0f) * 2.0f - 1.0f;
            qgrid[r] = g;
            refp[2*r]   = make_float4(uv[0], uv[1], uv[2], uv[3]);
            refp[2*r+1] = make_float4(uv[4], uv[5], uv[6], uv[7]);
            ranks[c][t] = r;
        } else {
            ranks[c][t] = -1;
        }
        // tail fill: slots >= row total get defaults (covers all slots once)
        if (q >= sTotal[c]) {
            qgrid[q] = make_float2(-1.5f, -1.5f);
            float4 z4 = make_float4(0.f, 0.f, 0.f, 0.f);
            refp[2*q]   = z4;
            refp[2*q+1] = z4;
        }
    }
    __syncthreads();

    // phase 2: restore grid + pillar counts straight from LDS ranks
    float2* rest = (float2*)(out + OFF_RESTORE) + (size_t)b * NCAM * NQ;
    int over = 0;
    #pragma unroll
    for (int c = 0; c < NCAM; ++c) {
        int r = ranks[c][t];
        if (r >= 0) {
            float gx = ((float)(r & 255) / 255.0f) * 2.0f - 1.0f;
            float gy = ((float)(c * 256 + (r >> 8)) / 1535.0f) * 2.0f - 1.0f;
            rest[(over * 256 + qy) * 256 + qx] = make_float2(gx, gy);
            ++over;
        }
    }
    for (int o = over; o < NCAM; ++o)
        rest[(o * 256 + qy) * 256 + qx] = make_float2(-1.5f, -1.5f);
    out[OFF_COUNTS + b * NQ + q] = 1.0f / fmaxf((float)over, 1.0f);
}

extern "C" void kernel_launch(void* const* d_in, const int* in_sizes, int n_in,
                              void* d_out, int out_size, void* d_ws, size_t ws_size,
                              hipStream_t stream)
{
    const float* ego2img = (const float*)d_in[0];
    float* out = (float*)d_out;
    int* chunkCounts = (int*)d_ws;   // 24*256 ints = 24.6 KB

    k_count<<<dim3(64, NROWS), 256, 0, stream>>>(ego2img, chunkCounts);
    k_fused<<<dim3(256, NB),   256, 0, stream>>>(ego2img, chunkCounts, out);
}